// Round 1
// baseline (595.631 us; speedup 1.0000x reference)
//
#include <hip/hip_runtime.h>
#include <cstdint>

#define BATCH 8
#define NPART 2048
#define DDIM 8
#define JCHUNK 1024
#define NN (NPART * NPART) /* 4194304 pairs per batch */

constexpr float LR = 0.1f;
constexpr float ALPHA = 0.9f;
constexpr float EPS = 1e-8f;
constexpr float INV_N = 1.0f / (float)NPART;

// ---------------------------------------------------------------------------
// init: zero RMSprop state s, zero radix histograms, init select states.
// rank is 1-indexed target order statistic among remaining candidates.
// median of even-count array = avg of order stats n/2 and n/2+1 (1-indexed).
// ---------------------------------------------------------------------------
__global__ __launch_bounds__(256) void init_ws_k(float* __restrict__ s,
                                                 unsigned* __restrict__ hist,
                                                 unsigned* __restrict__ prefix,
                                                 unsigned* __restrict__ rank) {
    const int tid = blockIdx.x * 256 + threadIdx.x;
    const int stride = gridDim.x * 256;
    for (int q = tid; q < BATCH * NPART * DDIM; q += stride) s[q] = 0.0f;
    if (tid < BATCH * 2 * 256) hist[tid] = 0u;
    if (tid < BATCH * 2) {
        prefix[tid] = 0u;
        rank[tid] = (unsigned)(NN / 2) + (unsigned)(tid & 1); // 2097152 / 2097153
    }
}

// ---------------------------------------------------------------------------
// radix-select histogram pass: count candidates (pairwise sq dist as uint32
// bit pattern, monotone for non-negative floats) matching each selection's
// current prefix, binned on the current 8-bit digit.
// grid: (BATCH, 64); block: 256 = 32 rows x 8 lanes.
// ---------------------------------------------------------------------------
__global__ __launch_bounds__(256) void median_hist_k(const float* __restrict__ x,
                                                     unsigned* __restrict__ hist,
                                                     const unsigned* __restrict__ prefix,
                                                     int shift) {
    __shared__ __align__(16) float xs[JCHUNK * DDIM]; // 32 KB j-chunk stage
    __shared__ unsigned lh[512];                      // 2 x 256 bins

    const int b = blockIdx.x;
    const int tid = threadIdx.x;
    const float* xb = x + (size_t)b * NPART * DDIM;

    lh[tid] = 0u;
    lh[tid + 256] = 0u;

    const unsigned p0 = prefix[2 * b + 0];
    const unsigned p1 = prefix[2 * b + 1];
    const unsigned mask = (shift == 24) ? 0u : (0xFFFFFFFFu << (shift + 8));

    const int lane = tid & 7;
    const int row = tid >> 3;
    const int i = blockIdx.y * 32 + row;

    const float4 xv0 = ((const float4*)(xb + (size_t)i * DDIM))[0];
    const float4 xv1 = ((const float4*)(xb + (size_t)i * DDIM))[1];
    const float xi0 = xv0.x, xi1 = xv0.y, xi2 = xv0.z, xi3 = xv0.w;
    const float xi4 = xv1.x, xi5 = xv1.y, xi6 = xv1.z, xi7 = xv1.w;

    for (int cbase = 0; cbase < NPART; cbase += JCHUNK) {
        __syncthreads(); // protect xs reuse (and cover lh zeroing first time)
        for (int t = tid; t < JCHUNK * DDIM / 4; t += 256)
            ((float4*)xs)[t] = ((const float4*)(xb + (size_t)cbase * DDIM))[t];
        __syncthreads();
        for (int j = lane; j < JCHUNK; j += 8) {
            const float4 a = ((const float4*)(xs + j * DDIM))[0];
            const float4 c4 = ((const float4*)(xs + j * DDIM))[1];
            float d, sq = 0.0f;
            d = xi0 - a.x;  sq = fmaf(d, d, sq);
            d = xi1 - a.y;  sq = fmaf(d, d, sq);
            d = xi2 - a.z;  sq = fmaf(d, d, sq);
            d = xi3 - a.w;  sq = fmaf(d, d, sq);
            d = xi4 - c4.x; sq = fmaf(d, d, sq);
            d = xi5 - c4.y; sq = fmaf(d, d, sq);
            d = xi6 - c4.z; sq = fmaf(d, d, sq);
            d = xi7 - c4.w; sq = fmaf(d, d, sq);
            const unsigned u = __float_as_uint(sq);
            const unsigned bin = (u >> shift) & 255u;
            if ((u & mask) == p0) atomicAdd(&lh[bin], 1u);
            if ((u & mask) == p1) atomicAdd(&lh[256 + bin], 1u);
        }
    }
    __syncthreads();
    const unsigned v0 = lh[tid];
    const unsigned v1 = lh[tid + 256];
    if (v0) atomicAdd(&hist[b * 512 + tid], v0);
    if (v1) atomicAdd(&hist[b * 512 + 256 + tid], v1);
}

// ---------------------------------------------------------------------------
// scan: per (batch, sel) find the digit bin containing the target rank,
// update prefix/rank, zero hist for the next round. After the final round
// (shift==0) compute h params: neg_inv_h = -1/h, two_over_h = 2/h where
// h = ((sqrt(v1)+sqrt(v2))/2)^2 / log(N).
// ---------------------------------------------------------------------------
__global__ void median_scan_k(unsigned* __restrict__ hist,
                              unsigned* __restrict__ prefix,
                              unsigned* __restrict__ rank,
                              int shift,
                              float* __restrict__ hpar) {
    __shared__ unsigned selv[16];
    const int t = threadIdx.x;
    if (t < 16) {
        const unsigned r = rank[t];
        const unsigned* hb = hist + t * 256;
        unsigned cum = 0;
        int bin = 0;
        for (; bin < 256; ++bin) {
            const unsigned c = hb[bin];
            if (cum + c >= r) break;
            cum += c;
        }
        if (bin > 255) bin = 255;
        const unsigned np = prefix[t] | ((unsigned)bin << shift);
        prefix[t] = np;
        rank[t] = r - cum;
        selv[t] = np;
    }
    __syncthreads();
    for (int q = t; q < 16 * 256; q += 64) hist[q] = 0u;
    if (shift == 0 && t < BATCH) {
        const float v1 = __uint_as_float(selv[2 * t + 0]);
        const float v2 = __uint_as_float(selv[2 * t + 1]);
        const float med = 0.5f * (sqrtf(v1) + sqrtf(v2));
        const float h = (med * med) / logf((float)NPART);
        hpar[2 * t + 0] = -1.0f / h;
        hpar[2 * t + 1] = 2.0f / h;
    }
}

// ---------------------------------------------------------------------------
// one SVGD + RMSprop step.
// phi_id = (1/N) * ( S0*(obs_d - x_id) + (1 + 2/h) * U_d ),
//   S0 = sum_j K_ij, U_d = sum_j K_ij (x_i - x_j)_d   (exactly the reference
//   terms: sum K g = S0*(obs-x_i) + U;  sum K dist = U).
// grid: (BATCH, 64); block 256 = 32 rows x 8 lanes; lane-partial sums are
// combined through a small LDS array (static indexing only).
// ---------------------------------------------------------------------------
__global__ __launch_bounds__(256) void svgd_step_k(const float* __restrict__ x_in,
                                                   float* __restrict__ x_out,
                                                   float* __restrict__ s,
                                                   const float* __restrict__ hpar,
                                                   const float* __restrict__ obs) {
    __shared__ __align__(16) float xs[JCHUNK * DDIM]; // 32 KB
    __shared__ float part[32][8][9];                  // 9 KB partials

    const int b = blockIdx.x;
    const int tid = threadIdx.x;
    const float* xb = x_in + (size_t)b * NPART * DDIM;

    const float nih = hpar[2 * b + 0]; // -1/h
    const float c2 = hpar[2 * b + 1];  //  2/h

    const int lane = tid & 7;
    const int row = tid >> 3;
    const int i = blockIdx.y * 32 + row;

    const float4 xv0 = ((const float4*)(xb + (size_t)i * DDIM))[0];
    const float4 xv1 = ((const float4*)(xb + (size_t)i * DDIM))[1];
    const float xi0 = xv0.x, xi1 = xv0.y, xi2 = xv0.z, xi3 = xv0.w;
    const float xi4 = xv1.x, xi5 = xv1.y, xi6 = xv1.z, xi7 = xv1.w;

    float S0 = 0.0f;
    float U0 = 0, U1 = 0, U2 = 0, U3 = 0, U4 = 0, U5 = 0, U6 = 0, U7 = 0;

    for (int cbase = 0; cbase < NPART; cbase += JCHUNK) {
        __syncthreads();
        for (int t = tid; t < JCHUNK * DDIM / 4; t += 256)
            ((float4*)xs)[t] = ((const float4*)(xb + (size_t)cbase * DDIM))[t];
        __syncthreads();
        for (int j = lane; j < JCHUNK; j += 8) {
            const float4 a = ((const float4*)(xs + j * DDIM))[0];
            const float4 c4 = ((const float4*)(xs + j * DDIM))[1];
            const float d0 = xi0 - a.x;
            const float d1 = xi1 - a.y;
            const float d2 = xi2 - a.z;
            const float d3 = xi3 - a.w;
            const float d4 = xi4 - c4.x;
            const float d5 = xi5 - c4.y;
            const float d6 = xi6 - c4.z;
            const float d7 = xi7 - c4.w;
            float sq = 0.0f;
            sq = fmaf(d0, d0, sq);
            sq = fmaf(d1, d1, sq);
            sq = fmaf(d2, d2, sq);
            sq = fmaf(d3, d3, sq);
            sq = fmaf(d4, d4, sq);
            sq = fmaf(d5, d5, sq);
            sq = fmaf(d6, d6, sq);
            sq = fmaf(d7, d7, sq);
            const float K = expf(sq * nih); // accurate exp: sign-sensitive dynamics
            S0 += K;
            U0 = fmaf(K, d0, U0);
            U1 = fmaf(K, d1, U1);
            U2 = fmaf(K, d2, U2);
            U3 = fmaf(K, d3, U3);
            U4 = fmaf(K, d4, U4);
            U5 = fmaf(K, d5, U5);
            U6 = fmaf(K, d6, U6);
            U7 = fmaf(K, d7, U7);
        }
    }
    part[row][lane][0] = S0;
    part[row][lane][1] = U0;
    part[row][lane][2] = U1;
    part[row][lane][3] = U2;
    part[row][lane][4] = U3;
    part[row][lane][5] = U4;
    part[row][lane][6] = U5;
    part[row][lane][7] = U6;
    part[row][lane][8] = U7;
    __syncthreads();

    // phase 2: thread (r2, d2) reduces 8 lane-partials and applies the update
    const int d2i = tid & 7;
    const int r2 = tid >> 3;
    const int i2 = blockIdx.y * 32 + r2;
    float S0t = 0.0f, Ut = 0.0f;
#pragma unroll
    for (int l = 0; l < 8; ++l) {
        S0t += part[r2][l][0];
        Ut += part[r2][l][1 + d2i];
    }
    const size_t idx = ((size_t)b * NPART + i2) * DDIM + d2i;
    const float xid = x_in[idx];
    const float obsd = obs[b * DDIM + d2i];
    const float T = fmaf(S0t, obsd - xid, Ut);      // sum_j K*(obs - x_j)
    const float phi = INV_N * fmaf(c2, Ut, T);      // + (2/h) * sum_j K*dist
    float sv = s[idx];
    sv = ALPHA * sv + (1.0f - ALPHA) * phi * phi;
    s[idx] = sv;
    x_out[idx] = xid + LR * phi / (sqrtf(sv) + EPS);
}

// ---------------------------------------------------------------------------
extern "C" void kernel_launch(void* const* d_in, const int* in_sizes, int n_in,
                              void* d_out, int out_size, void* d_ws, size_t ws_size,
                              hipStream_t stream) {
    const float* x0 = (const float*)d_in[0];   // [8,2048,8]
    const float* obs = (const float*)d_in[1];  // [8,8]
    float* out = (float*)d_out;                // [8,2048,8]

    // workspace layout (~1.07 MB)
    float* xa = (float*)d_ws;                          // 524288 B ping-pong x
    float* s = xa + BATCH * NPART * DDIM;              // 524288 B RMSprop state
    unsigned* hist = (unsigned*)(s + BATCH * NPART * DDIM); // 16384 B
    unsigned* prefix = hist + BATCH * 2 * 256;         // 64 B
    unsigned* rank = prefix + BATCH * 2;               // 64 B
    float* hpar = (float*)(rank + BATCH * 2);          // 64 B

    init_ws_k<<<256, 256, 0, stream>>>(s, hist, prefix, rank);

    // exact median via 4-round radix select on float bit patterns
    for (int r = 0; r < 4; ++r) {
        const int shift = 24 - 8 * r;
        median_hist_k<<<dim3(BATCH, 64), 256, 0, stream>>>(x0, hist, prefix, shift);
        median_scan_k<<<1, 64, 0, stream>>>(hist, prefix, rank, shift, hpar);
    }

    // 5 SVGD iterations, ping-ponging between d_out and ws; ends in d_out
    svgd_step_k<<<dim3(BATCH, 64), 256, 0, stream>>>(x0, out, s, hpar, obs);
    svgd_step_k<<<dim3(BATCH, 64), 256, 0, stream>>>(out, xa, s, hpar, obs);
    svgd_step_k<<<dim3(BATCH, 64), 256, 0, stream>>>(xa, out, s, hpar, obs);
    svgd_step_k<<<dim3(BATCH, 64), 256, 0, stream>>>(out, xa, s, hpar, obs);
    svgd_step_k<<<dim3(BATCH, 64), 256, 0, stream>>>(xa, out, s, hpar, obs);
}